// Round 1
// baseline (110.061 us; speedup 1.0000x reference)
//
#include <hip/hip_runtime.h>
#include <hip/hip_bf16.h>

// ModConv2d: per-sample modulated 3x3 conv (N=8, C=64->64, 256x256) + MLPs.
// Kernel 1: MLPs -> w_bf[n][kidx][cout][ci] (bf16, ci-contiguous) + bias[n][cout] in d_ws.
// Kernel 2: implicit-GEMM conv with mfma_f32_16x16x32_bf16.
//   Block: 1 sample x 2 output rows x 256 cols x 64 couts. 4 waves:
//   wave = (row within pair, col half); per wave M_rep=4 cout-tiles x N_rep=8 px-tiles.
//   K-order: ci-major within (chunk,kidx): K=32 = 32 consecutive ci at fixed kidx.
//   LDS: x [4][258][32ci] bf16, w-entry stride padded to 5x16B slots (bank spread);
//        weights [9][64][64] bf16 XOR-swizzled by cout (A-frag conflict fix).

typedef short bf16x8 __attribute__((ext_vector_type(8)));
typedef float f32x4 __attribute__((ext_vector_type(4)));

#define NB 8
#define CIN 64
#define COUT 64
#define HH 256
#define WW 256
#define HWP (HH * WW)
#define AUXD 128
#define HIDD 256

#define XSLOTS 5                      // 16B slots per (r,wi) entry (4 data + 1 pad)
#define XBYTES (4 * 258 * XSLOTS * 16)  // 82560
#define WBYTES (9 * 64 * 64 * 2)        // 73728

__device__ __forceinline__ unsigned short f2bf(float f) {
    unsigned u = __builtin_bit_cast(unsigned, f);
    u += 0x7FFFu + ((u >> 16) & 1u);   // RNE (inputs are well-behaved, no NaN care)
    return (unsigned short)(u >> 16);
}

__device__ __forceinline__ void mfma16(f32x4& d, bf16x8 a, bf16x8 b) {
    asm volatile("v_mfma_f32_16x16x32_bf16 %0, %1, %2, %0"
                 : "+v"(d) : "v"(a), "v"(b));
}

// ---------------- Kernel 1: MLPs ----------------
// grid (17, 8): x = 0..15 -> modulation chunk of 256 outputs; x = 16 -> bias MLP.
__global__ __launch_bounds__(256) void mlp_kernel(
    const float* __restrict__ y, const float* __restrict__ weight,
    const float* __restrict__ fc_w1, const float* __restrict__ fc_b1,
    const float* __restrict__ fc_prelu,
    const float* __restrict__ fc_w2, const float* __restrict__ fc_b2,
    const float* __restrict__ bias_w1, const float* __restrict__ bias_b1,
    const float* __restrict__ bias_prelu,
    const float* __restrict__ bias_w2, const float* __restrict__ bias_b2,
    unsigned short* __restrict__ w_bf, float* __restrict__ bvec)
{
    const int n = blockIdx.y;
    const int c = blockIdx.x;
    const int tid = threadIdx.x;
    __shared__ float ylds[AUXD];
    __shared__ float hl[HIDD];
    if (tid < AUXD) ylds[tid] = y[n * AUXD + tid];
    __syncthreads();

    if (c < 16) {
        // hidden layer of modulation MLP (recomputed per block; tiny)
        float s = fc_b1[tid];
        const float* wrow = fc_w1 + tid * AUXD;
        #pragma unroll 4
        for (int a = 0; a < AUXD; ++a) s += ylds[a] * wrow[a];
        float ap = fc_prelu[0];
        hl[tid] = s >= 0.f ? s : ap * s;
        __syncthreads();

        int o = c * 256 + tid;           // o = cout*64 + ci
        float t = fc_b2[o];
        const float* w2row = fc_w2 + o * HIDD;
        #pragma unroll 4
        for (int h = 0; h < HIDD; ++h) t += hl[h] * w2row[h];
        float mod = 1.f / (1.f + expf(-t));
        int cout = o >> 6, ci = o & 63;
        #pragma unroll
        for (int k = 0; k < 9; ++k) {
            float wv = weight[o * 9 + k];  // ((cout*64+ci)*3+kh)*3+kw = o*9+k
            w_bf[((n * 9 + k) * COUT + cout) * CIN + ci] = f2bf(mod * wv);
        }
    } else {
        float s = bias_b1[tid];
        const float* wrow = bias_w1 + tid * AUXD;
        #pragma unroll 4
        for (int a = 0; a < AUXD; ++a) s += ylds[a] * wrow[a];
        float ap = bias_prelu[0];
        hl[tid] = s >= 0.f ? s : ap * s;
        __syncthreads();
        if (tid < COUT) {
            float t = bias_b2[tid];
            const float* w2row = bias_w2 + tid * HIDD;
            #pragma unroll 4
            for (int h = 0; h < HIDD; ++h) t += hl[h] * w2row[h];
            bvec[n * COUT + tid] = t;
        }
    }
}

// ---------------- Kernel 2: conv ----------------
__global__ __launch_bounds__(256, 1) void conv_kernel(
    const float* __restrict__ x, const unsigned short* __restrict__ w_bf,
    const float* __restrict__ bvec, float* __restrict__ out)
{
    __shared__ __align__(16) unsigned char smem[XBYTES + WBYTES];
    unsigned char* xb = smem;
    unsigned char* wbs = smem + XBYTES;

    const int bid = blockIdx.x;
    const int swz = (bid & 7) * 128 + (bid >> 3);  // XCD k -> sample k, rows in order
    const int n = swz >> 7;
    const int h0 = (swz & 127) * 2;

    const int tid = threadIdx.x;
    const int lane = tid & 63;
    const int wave = tid >> 6;
    const int px = lane & 15;
    const int q = lane >> 4;
    const int wr = wave >> 1;            // output row within pair
    const int wcol0 = (wave & 1) * 128;  // col half base

    // ---- stage all weights for this sample: 4608 x 16B chunks ----
    {
        const uint4* src = (const uint4*)(w_bf + n * (9 * 64 * 64));
        #pragma unroll 3
        for (int it = 0; it < 18; ++it) {
            int idx = it * 256 + tid;            // = kidx*512 + cout*8 + cb2
            uint4 v = src[idx];
            int cout = (idx >> 3) & 63;
            int a16 = idx ^ (cout & 7);
            *(uint4*)(wbs + (a16 << 4)) = v;
        }
    }

    f32x4 acc[4][8];
    #pragma unroll
    for (int m = 0; m < 4; ++m)
        #pragma unroll
        for (int j = 0; j < 8; ++j)
            acc[m][j] = (f32x4){0.f, 0.f, 0.f, 0.f};

    #pragma unroll
    for (int chunk = 0; chunk < 2; ++chunk) {
        if (chunk) __syncthreads();  // drain reads of buffer before overwrite
        // zero halo columns (input col -1 and 256)
        if (tid < 32) {
            int r = tid >> 3;
            int wi = ((tid >> 2) & 1) ? 257 : 0;
            int slot = tid & 3;
            uint4 z; z.x = z.y = z.z = z.w = 0u;
            *(uint4*)(xb + (((r * 258 + wi) * XSLOTS + slot) << 4)) = z;
        }
        // main fill: 4 input rows x 256 w x 32 ci (f32 -> bf16, NCHW -> [r][w][ci])
        const int ci0 = chunk * 32;
        #pragma unroll 4
        for (int it = 0; it < 32; ++it) {
            int idx = it * 256 + tid;
            int w = idx & 255;           // lane-contiguous -> coalesced
            int rc = idx >> 8;           // 0..31
            int r = rc >> 3;
            int c0 = (rc & 7) * 4;
            int hin = h0 - 1 + r;
            bool val = (hin >= 0) && (hin < HH);
            int hinc = val ? hin : 0;
            float vm = val ? 1.f : 0.f;
            const float* xp = x + (((n * CIN + ci0 + c0) * HH + hinc) * WW + w);
            float f0 = xp[0 * HWP] * vm;
            float f1 = xp[1 * HWP] * vm;
            float f2 = xp[2 * HWP] * vm;
            float f3 = xp[3 * HWP] * vm;
            ushort4 pk;
            pk.x = f2bf(f0); pk.y = f2bf(f1); pk.z = f2bf(f2); pk.w = f2bf(f3);
            *(ushort4*)(xb + ((((r * 258 + (w + 1)) * XSLOTS) << 4) + (c0 << 1))) = pk;
        }
        __syncthreads();

        // ---- compute: 9 kidx, K=32 each ----
        #pragma unroll
        for (int kidx = 0; kidx < 9; ++kidx) {
            const int kh = kidx / 3, kw = kidx - kh * 3;
            bf16x8 afrag[4];
            #pragma unroll
            for (int m = 0; m < 4; ++m) {
                int a16 = (kidx * 512 + (m * 16 + px) * 8 + chunk * 4 + q) ^ (px & 7);
                afrag[m] = *(const bf16x8*)(wbs + (a16 << 4));
            }
            bf16x8 bfrag[8];
            #pragma unroll
            for (int j = 0; j < 8; ++j) {
                int wi = wcol0 + j * 16 + px + kw;
                bfrag[j] = *(const bf16x8*)(xb + ((((wr + kh) * 258 + wi) * XSLOTS + q) << 4));
            }
            #pragma unroll
            for (int m = 0; m < 4; ++m)
                #pragma unroll
                for (int j = 0; j < 8; ++j)
                    mfma16(acc[m][j], afrag[m], bfrag[j]);
        }
    }

    // ---- epilogue: D col = lane&15 (px), row = q*4 + t (cout offset) ----
    const int hout = h0 + wr;
    float bias_r[4][4];
    #pragma unroll
    for (int m = 0; m < 4; ++m)
        #pragma unroll
        for (int t = 0; t < 4; ++t)
            bias_r[m][t] = bvec[n * COUT + m * 16 + q * 4 + t];
    #pragma unroll
    for (int m = 0; m < 4; ++m) {
        #pragma unroll
        for (int j = 0; j < 8; ++j) {
            int wbcol = wcol0 + j * 16 + px;
            #pragma unroll
            for (int t = 0; t < 4; ++t) {
                int cout = m * 16 + q * 4 + t;
                out[((n * COUT + cout) * HH + hout) * WW + wbcol] = acc[m][j][t] + bias_r[m][t];
            }
        }
    }
}

extern "C" void kernel_launch(void* const* d_in, const int* in_sizes, int n_in,
                              void* d_out, int out_size, void* d_ws, size_t ws_size,
                              hipStream_t stream) {
    const float* x          = (const float*)d_in[0];
    const float* y          = (const float*)d_in[1];
    const float* weight     = (const float*)d_in[2];
    const float* fc_w1      = (const float*)d_in[3];
    const float* fc_b1      = (const float*)d_in[4];
    const float* fc_prelu   = (const float*)d_in[5];
    const float* fc_w2      = (const float*)d_in[6];
    const float* fc_b2      = (const float*)d_in[7];
    const float* bias_w1    = (const float*)d_in[8];
    const float* bias_b1    = (const float*)d_in[9];
    const float* bias_prelu = (const float*)d_in[10];
    const float* bias_w2    = (const float*)d_in[11];
    const float* bias_b2    = (const float*)d_in[12];
    float* out = (float*)d_out;

    unsigned short* w_bf = (unsigned short*)d_ws;                       // 589824 B
    float* bvec = (float*)((char*)d_ws + (size_t)NB * 9 * 64 * 64 * 2); // 2048 B

    hipLaunchKernelGGL(mlp_kernel, dim3(17, 8), dim3(256), 0, stream,
                       y, weight, fc_w1, fc_b1, fc_prelu, fc_w2, fc_b2,
                       bias_w1, bias_b1, bias_prelu, bias_w2, bias_b2, w_bf, bvec);
    hipLaunchKernelGGL(conv_kernel, dim3(1024), dim3(256), 0, stream,
                       x, w_bf, bvec, out);
}

// Round 2
// 97.354 us; speedup vs baseline: 1.1305x; 1.1305x over previous
//
#include <hip/hip_runtime.h>
#include <hip/hip_bf16.h>

// ModConv2d: per-sample modulated 3x3 conv (N=8, C=64->64, 256x256) + MLPs.
// Kernel 1: MLPs -> w_bf[n][kidx][cout][ci] (bf16) + bias[n][cout] in d_ws.
// Kernel 2: implicit-GEMM conv, mfma_f32_16x16x32_bf16, double-buffered staging:
//   ci chunks of 16; K=32 step = (kidxA ci0..15, kidxB ci0..15) pairing
//   steps per chunk: (0,1)(2,3)(4,5)(6,7)(8,pad-zero). A-pad = uniform 16B zero slot.
//   Pipeline per chunk: {issue grp g+1 loads | compute step | cvt+write grp g}, 1 barrier.
//   x LDS entry stride 40B (32B data + 8 pad) -> staging writes uniform-4 banks.

typedef short bf16x8 __attribute__((ext_vector_type(8)));
typedef float f32x4 __attribute__((ext_vector_type(4)));

#define NB 8
#define CIN 64
#define COUT 64
#define HH 256
#define WW 256
#define HWP (HH * WW)
#define AUXD 128
#define HIDD 256

#define XENT 40
#define XROW (258 * XENT)      // 10320
#define XBUF (4 * XROW)        // 41280
#define WOFF (2 * XBUF)        // 82560
#define WBYTES (9 * 64 * 64 * 2)  // 73728
#define PADOFF (WOFF + WBYTES)
#define PAD16U (WBYTES >> 4)   // 4608 (16B-unit index of zero slot, relative to WOFF)
#define SMEMB (PADOFF + 16)    // 156304

__device__ __forceinline__ unsigned short f2bf(float f) {
    unsigned u = __builtin_bit_cast(unsigned, f);
    u += 0x7FFFu + ((u >> 16) & 1u);   // RNE
    return (unsigned short)(u >> 16);
}

__device__ __forceinline__ void mfma16(f32x4& d, bf16x8 a, bf16x8 b) {
    asm volatile("v_mfma_f32_16x16x32_bf16 %0, %1, %2, %0"
                 : "+v"(d) : "v"(a), "v"(b));
}

// ---------------- Kernel 1: MLPs (unchanged, proven) ----------------
__global__ __launch_bounds__(256) void mlp_kernel(
    const float* __restrict__ y, const float* __restrict__ weight,
    const float* __restrict__ fc_w1, const float* __restrict__ fc_b1,
    const float* __restrict__ fc_prelu,
    const float* __restrict__ fc_w2, const float* __restrict__ fc_b2,
    const float* __restrict__ bias_w1, const float* __restrict__ bias_b1,
    const float* __restrict__ bias_prelu,
    const float* __restrict__ bias_w2, const float* __restrict__ bias_b2,
    unsigned short* __restrict__ w_bf, float* __restrict__ bvec)
{
    const int n = blockIdx.y;
    const int c = blockIdx.x;
    const int tid = threadIdx.x;
    __shared__ float ylds[AUXD];
    __shared__ float hl[HIDD];
    if (tid < AUXD) ylds[tid] = y[n * AUXD + tid];
    __syncthreads();

    if (c < 16) {
        float s = fc_b1[tid];
        const float* wrow = fc_w1 + tid * AUXD;
        #pragma unroll 4
        for (int a = 0; a < AUXD; ++a) s += ylds[a] * wrow[a];
        float ap = fc_prelu[0];
        hl[tid] = s >= 0.f ? s : ap * s;
        __syncthreads();

        int o = c * 256 + tid;           // o = cout*64 + ci
        float t = fc_b2[o];
        const float* w2row = fc_w2 + o * HIDD;
        #pragma unroll 4
        for (int h = 0; h < HIDD; ++h) t += hl[h] * w2row[h];
        float mod = 1.f / (1.f + expf(-t));
        int cout = o >> 6, ci = o & 63;
        #pragma unroll
        for (int k = 0; k < 9; ++k) {
            float wv = weight[o * 9 + k];
            w_bf[((n * 9 + k) * COUT + cout) * CIN + ci] = f2bf(mod * wv);
        }
    } else {
        float s = bias_b1[tid];
        const float* wrow = bias_w1 + tid * AUXD;
        #pragma unroll 4
        for (int a = 0; a < AUXD; ++a) s += ylds[a] * wrow[a];
        float ap = bias_prelu[0];
        hl[tid] = s >= 0.f ? s : ap * s;
        __syncthreads();
        if (tid < COUT) {
            float t = bias_b2[tid];
            const float* w2row = bias_w2 + tid * HIDD;
            #pragma unroll 4
            for (int h = 0; h < HIDD; ++h) t += hl[h] * w2row[h];
            bvec[n * COUT + tid] = t;
        }
    }
}

// ---------------- Kernel 2: conv ----------------
__global__ __launch_bounds__(256, 1) void conv_kernel(
    const float* __restrict__ x, const unsigned short* __restrict__ w_bf,
    const float* __restrict__ bvec, float* __restrict__ out)
{
    __shared__ __align__(16) unsigned char smem[SMEMB];

    const int bid = blockIdx.x;
    const int swz = (bid & 7) * 128 + (bid >> 3);  // XCD k -> sample k, rows in order
    const int n = swz >> 7;
    const int h0 = (swz & 127) * 2;

    const int tid = threadIdx.x;
    const int lane = tid & 63;
    const int wave = tid >> 6;
    const int px = lane & 15;
    const int q = lane >> 4;
    const int q01 = q & 1;
    const int qhi = q >> 1;
    const int wr = wave >> 1;            // output row within pair
    const int w0 = (wave & 1) * 128;     // col half base
    const int w = tid;                   // staging column 0..255

    // per-input-row staging bases (row g = input row h0-1+g, clamped + mask)
    const float* xrow[4];
    float vmr[4];
    #pragma unroll
    for (int g = 0; g < 4; ++g) {
        int hin = h0 - 1 + g;
        bool val = (hin >= 0) && (hin < HH);
        xrow[g] = x + (size_t)n * CIN * HWP + (size_t)(val ? hin : 0) * WW + w;
        vmr[g] = val ? 1.f : 0.f;
    }

    // ---- stage all weights for this sample + zero pad slot + halo columns ----
    {
        const uint4* src = (const uint4*)(w_bf + n * (9 * 64 * 64));
        #pragma unroll
        for (int it = 0; it < 18; ++it) {
            int idx = it * 256 + tid;            // = kidx*512 + cout*8 + cb2
            uint4 v = src[idx];
            int cout = (idx >> 3) & 63;
            int a16 = idx ^ (cout & 7);
            *(uint4*)(smem + WOFF + (a16 << 4)) = v;
        }
        if (tid == 0) {
            uint4 z; z.x = z.y = z.z = z.w = 0u;
            *(uint4*)(smem + PADOFF) = z;
        }
        // halo entries wi=0 (col -1) and wi=257 (col 256): zero once, never rewritten
        if (tid < 64) {
            int buf = tid >> 5, r = (tid >> 3) & 3;
            int wi = ((tid >> 2) & 1) ? 257 : 0;
            int s = tid & 3;
            *(unsigned long long*)(smem + buf * XBUF + r * XROW + wi * XENT + s * 8) = 0ULL;
        }
    }

    // ---- prologue: stage chunk 0 (ci 0..15) -> buf0 ----
    float st[16];
    #pragma unroll
    for (int g = 0; g < 4; ++g) {
        #pragma unroll
        for (int i = 0; i < 4; ++i)
            #pragma unroll
            for (int t = 0; t < 4; ++t)
                st[i * 4 + t] = xrow[g][(size_t)(i * 4 + t) * HWP];
        float vm = vmr[g];
        #pragma unroll
        for (int i = 0; i < 4; ++i) {
            ushort4 pk;
            pk.x = f2bf(st[i * 4 + 0] * vm); pk.y = f2bf(st[i * 4 + 1] * vm);
            pk.z = f2bf(st[i * 4 + 2] * vm); pk.w = f2bf(st[i * 4 + 3] * vm);
            *(ushort4*)(smem + g * XROW + (w + 1) * XENT + i * 8) = pk;
        }
    }

    f32x4 acc[4][8];
    #pragma unroll
    for (int m = 0; m < 4; ++m)
        #pragma unroll
        for (int j = 0; j < 8; ++j)
            acc[m][j] = (f32x4){0.f, 0.f, 0.f, 0.f};

    __syncthreads();

    // step s: K=32 from (kidxA = 2s, kidxB = 2s+1); s=4: kidx 8 + zero pad
    for (int c = 0; c < 4; ++c) {
        const int xo = (c & 1) * XBUF;
        const int nx = ((c & 1) ^ 1) * XBUF;
        const int cn16 = (c + 1) * 16;
        const int oc2 = c * 2;
        const bool more = (c < 3);

        if (more) {
            #pragma unroll
            for (int i = 0; i < 4; ++i)
                #pragma unroll
                for (int t = 0; t < 4; ++t)
                    st[i * 4 + t] = xrow[0][(size_t)(cn16 + i * 4 + t) * HWP];
        }

        #pragma unroll
        for (int s = 0; s < 5; ++s) {
            const int ka = 2 * s;                   // 0,2,4,6,8
            const int kb = (s == 4) ? 8 : 2 * s + 1;
            const int khA_ = ka / 3, kwA_ = ka % 3;
            const int khB_ = kb / 3, kwB_ = kb % 3;
            const bool solo = (s == 4);

            int kh = qhi ? khB_ : khA_;
            int kw = qhi ? kwB_ : kwA_;
            int kidx_m = qhi ? kb : ka;
            bool padA = solo && (qhi != 0);
            int areal = (kidx_m * 512 + px * 8 + oc2 + q01) ^ (px & 7);
            int abase = padA ? PAD16U : areal;
            int am = padA ? 0 : 128;

            bf16x8 af[4];
            #pragma unroll
            for (int m = 0; m < 4; ++m)
                af[m] = *(const bf16x8*)(smem + WOFF + ((abase + m * am) << 4));

            int bb = xo + (wr + kh) * XROW + (w0 + px + kw) * XENT + q01 * 16;
            bf16x8 bfr[8];
            #pragma unroll
            for (int j = 0; j < 8; ++j)
                bfr[j] = *(const bf16x8*)(smem + bb + j * (16 * XENT));

            #pragma unroll
            for (int m = 0; m < 4; ++m)
                #pragma unroll
                for (int j = 0; j < 8; ++j)
                    mfma16(acc[m][j], af[m], bfr[j]);

            // staging interleave: write grp s (loads issued earlier), issue grp s+1
            if (more && s < 4) {
                const int g = s;
                float vm = vmr[g];
                #pragma unroll
                for (int i = 0; i < 4; ++i) {
                    ushort4 pk;
                    pk.x = f2bf(st[i * 4 + 0] * vm); pk.y = f2bf(st[i * 4 + 1] * vm);
                    pk.z = f2bf(st[i * 4 + 2] * vm); pk.w = f2bf(st[i * 4 + 3] * vm);
                    *(ushort4*)(smem + nx + g * XROW + (w + 1) * XENT + i * 8) = pk;
                }
                if (s < 3) {
                    const int g2 = s + 1;
                    #pragma unroll
                    for (int i = 0; i < 4; ++i)
                        #pragma unroll
                        for (int t = 0; t < 4; ++t)
                            st[i * 4 + t] = xrow[g2][(size_t)(cn16 + i * 4 + t) * HWP];
                }
            }
        }
        __syncthreads();
    }

    // ---- epilogue: D col = px, row = q*4 + t (cout offset) ----
    const int hout = h0 + wr;
    float bias_r[4][4];
    #pragma unroll
    for (int m = 0; m < 4; ++m)
        #pragma unroll
        for (int t = 0; t < 4; ++t)
            bias_r[m][t] = bvec[n * COUT + m * 16 + q * 4 + t];
    #pragma unroll
    for (int m = 0; m < 4; ++m) {
        #pragma unroll
        for (int j = 0; j < 8; ++j) {
            int wbcol = w0 + j * 16 + px;
            #pragma unroll
            for (int t = 0; t < 4; ++t) {
                int cout = m * 16 + q * 4 + t;
                out[((n * COUT + cout) * HH + hout) * WW + wbcol] = acc[m][j][t] + bias_r[m][t];
            }
        }
    }
}

extern "C" void kernel_launch(void* const* d_in, const int* in_sizes, int n_in,
                              void* d_out, int out_size, void* d_ws, size_t ws_size,
                              hipStream_t stream) {
    const float* x          = (const float*)d_in[0];
    const float* y          = (const float*)d_in[1];
    const float* weight     = (const float*)d_in[2];
    const float* fc_w1      = (const float*)d_in[3];
    const float* fc_b1      = (const float*)d_in[4];
    const float* fc_prelu   = (const float*)d_in[5];
    const float* fc_w2      = (const float*)d_in[6];
    const float* fc_b2      = (const float*)d_in[7];
    const float* bias_w1    = (const float*)d_in[8];
    const float* bias_b1    = (const float*)d_in[9];
    const float* bias_prelu = (const float*)d_in[10];
    const float* bias_w2    = (const float*)d_in[11];
    const float* bias_b2    = (const float*)d_in[12];
    float* out = (float*)d_out;

    unsigned short* w_bf = (unsigned short*)d_ws;                       // 589824 B
    float* bvec = (float*)((char*)d_ws + (size_t)NB * 9 * 64 * 64 * 2); // 2048 B

    hipLaunchKernelGGL(mlp_kernel, dim3(17, 8), dim3(256), 0, stream,
                       y, weight, fc_w1, fc_b1, fc_prelu, fc_w2, fc_b2,
                       bias_w1, bias_b1, bias_prelu, bias_w2, bias_b2, w_bf, bvec);
    hipLaunchKernelGGL(conv_kernel, dim3(1024), dim3(256), 0, stream,
                       x, w_bf, bvec, out);
}